// Round 4
// baseline (163.922 us; speedup 1.0000x reference)
//
#include <hip/hip_runtime.h>
#include <stdint.h>

// SimCLR loss, B=4096, D=512, TAU=0.1.  out[0]=loss, out[1]=acc(%).
//
// Round 14: R10's verified 62.9us schedule (64-col tiles, 2x32KB dbuf, ONE
// __syncthreads per iter, 16-MFMA clusters) with exactly two changes:
//  1. Full 5-bit XOR swizzle (stage src ^(cl&31), read ^n5) -- the math R13
//     measured at ZERO bank conflicts (R10's 3-bit variant: 4.19M 4-way,
//     ~1.58x on the ds_read critical path).
//  2. finalize fused into tiles via last-block-done (threadfence + atomic
//     counter): one fewer dispatch; probes the ~60us non-tiles gap.
// Also: s_setprio(1) around the MFMA cluster (T5; 2 waves/SIMD drift into
// anti-phase between barriers), #pragma unroll 1 on outer loops (R12 lesson:
// full unroll -> cross-iter hoisting -> spill).
// NOT kept from R13: 32-col tiles / counted vmcnt / sched_barrier walls --
// measured 73.4us, LOST to R10's plain dbuf (m196/m252: coarse phase split
// without fine interleave hurts; R10's long phase absorbs DMA latency).

#define BN 4096
#define DK 512            // K elements = bytes per row in fp8
#define NSPLIT 16
#define NEG_BIG -1e30f
#define SCL 0.15625f      // 1/(8*8*TAU)
#define SCL2 0.225396744f // SCL * log2(e)
#define C2 14.4269504f    // 10 * log2(e)
#define TILE_BYTES (64 * DK)  // 32 KB per 64-col fp8 tile

typedef __attribute__((ext_vector_type(16))) float floatx16;
typedef __attribute__((ext_vector_type(8))) int intx8;

// ---------------- prep: normalize, fp8-pack (K-permuted), label, zero -----
// Permuted layout: byte position kc2*32 + h*16 + t*8 + j holds original
// k = kc2*32 + t*16 + h*8 + j.  16B chunk (kc2,h) = K=16-sub-block operand
// bytes; two consecutive chunks (2i,h),(2i+1,h) = one K=64 MX operand half.
__global__ void __launch_bounds__(256) prep_kernel(
    const float* __restrict__ A, const float* __restrict__ Bv,
    unsigned char* __restrict__ An, unsigned char* __restrict__ Bn,
    float* __restrict__ diag, float* __restrict__ out,
    unsigned int* __restrict__ cnt) {
  if (blockIdx.x == 0 && threadIdx.x < 2) out[threadIdx.x] = 0.0f;
  if (blockIdx.x == 0 && threadIdx.x == 2) cnt[0] = 0u;
  const int w = threadIdx.x >> 6, lane = threadIdx.x & 63;
  const int row = blockIdx.x * 4 + w;
  const float4* pa4 = (const float4*)(A + (size_t)row * DK);
  const float4* pb4 = (const float4*)(Bv + (size_t)row * DK);
  float4 a0 = pa4[lane * 2], a1 = pa4[lane * 2 + 1];  // k = lane*8 .. +7
  float4 b0 = pb4[lane * 2], b1 = pb4[lane * 2 + 1];
  float ssa = a0.x * a0.x + a0.y * a0.y + a0.z * a0.z + a0.w * a0.w +
              a1.x * a1.x + a1.y * a1.y + a1.z * a1.z + a1.w * a1.w;
  float ssb = b0.x * b0.x + b0.y * b0.y + b0.z * b0.z + b0.w * b0.w +
              b1.x * b1.x + b1.y * b1.y + b1.z * b1.z + b1.w * b1.w;
  float sab = a0.x * b0.x + a0.y * b0.y + a0.z * b0.z + a0.w * b0.w +
              a1.x * b1.x + a1.y * b1.y + a1.z * b1.z + a1.w * b1.w;
#pragma unroll
  for (int off = 32; off > 0; off >>= 1) {
    ssa += __shfl_xor(ssa, off);
    ssb += __shfl_xor(ssb, off);
    sab += __shfl_xor(sab, off);
  }
  float na = fmaxf(sqrtf(ssa), 1e-12f);
  float nb = fmaxf(sqrtf(ssb), 1e-12f);
  const float s = 8.0f;  // fp8 pre-scale: keeps elems mid-range in e4m3
  float sa = s / na, sb = s / nb;
  const int doff = (lane >> 2) * 32 + (lane & 1) * 16 + ((lane >> 1) & 1) * 8;
  {
    int v0 = __builtin_amdgcn_cvt_pk_fp8_f32(a0.x * sa, a0.y * sa, 0, false);
    v0 = __builtin_amdgcn_cvt_pk_fp8_f32(a0.z * sa, a0.w * sa, v0, true);
    int v1 = __builtin_amdgcn_cvt_pk_fp8_f32(a1.x * sa, a1.y * sa, 0, false);
    v1 = __builtin_amdgcn_cvt_pk_fp8_f32(a1.z * sa, a1.w * sa, v1, true);
    int2 pv; pv.x = v0; pv.y = v1;
    *(int2*)(An + (size_t)row * DK + doff) = pv;
  }
  {
    int v0 = __builtin_amdgcn_cvt_pk_fp8_f32(b0.x * sb, b0.y * sb, 0, false);
    v0 = __builtin_amdgcn_cvt_pk_fp8_f32(b0.z * sb, b0.w * sb, v0, true);
    int v1 = __builtin_amdgcn_cvt_pk_fp8_f32(b1.x * sb, b1.y * sb, 0, false);
    v1 = __builtin_amdgcn_cvt_pk_fp8_f32(b1.z * sb, b1.w * sb, v1, true);
    int2 pv; pv.x = v0; pv.y = v1;
    *(int2*)(Bn + (size_t)row * DK + doff) = pv;
  }
  if (lane == 0) diag[row] = (sab / (na * nb)) * 10.0f;  // exact fp32 /TAU
}

// ---------------- tiles: MX fp8 MFMA, R10 dbuf schedule + 5-bit swizzle ---
// grid = (32 row-blocks, 16 col-splits) = 512 blocks = 2/CU. 4 waves/block,
// wave owns 32 rows. Split covers 512 cols of ONE view (0-7: An, 8-15: Bn).
// u<8: a-row frags -> full_a sums+max. u>=8: b-row frags -> full_b sums.
// Last block to finish runs the finalize reduction (fence + atomic counter).
__global__ void __launch_bounds__(256, 2) tiles_kernel(
    const unsigned char* __restrict__ An, const unsigned char* __restrict__ Bn,
    float* __restrict__ pSA, float* __restrict__ pMA, float* __restrict__ pSB,
    const float* __restrict__ diag, float* __restrict__ out,
    unsigned int* __restrict__ cnt) {
  __shared__ __align__(16) unsigned char smem[2 * TILE_BYTES];  // 64 KB
  __shared__ unsigned int s_last;

  const int rb = blockIdx.x;     // 0..31 (128-row panel)
  const int split = blockIdx.y;  // 0..15
  const int tid = threadIdx.x;
  const int lane = tid & 63, w = tid >> 6;
  const int n5 = lane & 31, h = lane >> 5;
  const int r0 = rb * 128;
  const int myrow = r0 + w * 32 + n5;
  const int csplit = split & 7;
  const unsigned char* __restrict__ csrc = (split < 8) ? An : Bn;

  // K=64 MX row operands (ONE view at a time): aw[i] = chunks (2i,h)||(2i+1,h)
  intx8 aw[8];
  auto loadfrags = [&](const unsigned char* base) {
    const unsigned char* p = base + (size_t)myrow * DK + h * 16;
#pragma unroll
    for (int i = 0; i < 8; ++i) {
      int4 c0 = *(const int4*)(p + i * 64);
      int4 c1 = *(const int4*)(p + i * 64 + 32);
      intx8 v = {c0.x, c0.y, c0.z, c0.w, c1.x, c1.y, c1.z, c1.w};
      aw[i] = v;
    }
  };

  // stage a 64-col tile (32 KB): wave w stages colpairs w*8..w*8+7.
  // DMA dest linear (base + laneid*16); 5-bit swizzle via pre-swizzled
  // global source: physical chunk p of col cl holds logical chunk p^(cl&31).
  auto stage = [&](unsigned char* buf, int t) {
    const int cb = csplit * 512 + t * 64;
#pragma unroll
    for (int ii = 0; ii < 8; ++ii) {
      const int cp = w * 8 + ii;
      const int cl = cp * 2 + h;
      const unsigned char* src =
          csrc + (size_t)(cb + cl) * DK + ((n5 ^ (cl & 31)) * 16);
      __builtin_amdgcn_global_load_lds(
          (const __attribute__((address_space(1))) void*)src,
          (__attribute__((address_space(3))) void*)(buf + cp * 1024),
          16, 0, 0);
    }
  };

  float l[16], mx[16];
#pragma unroll
  for (int r = 0; r < 16; ++r) { l[r] = 0.f; mx[r] = NEG_BIG; }

  loadfrags(An);
  stage(smem, 0);
  __syncthreads();  // compiler drains vmcnt(0): tile 0 landed for all waves

#pragma unroll 1
  for (int u = 0; u < 16; ++u) {
    const int t = u & 7;
    unsigned char* cur = smem + (u & 1) * TILE_BYTES;
    unsigned char* nxt = smem + ((u + 1) & 1) * TILE_BYTES;
    if (u < 15) stage(nxt, (t + 1) & 7);  // prefetch next tile

    floatx16 acc0, acc1;
#pragma unroll
    for (int r = 0; r < 16; ++r) { acc0[r] = 0.f; acc1[r] = 0.f; }

    // col (cs*32+n5)'s K=64 operand: logical chunks (4i+h),(4i+2+h), phys ^n5
    const unsigned char* bbase = cur + (size_t)n5 * DK;
    __builtin_amdgcn_s_setprio(1);
#pragma unroll
    for (int i = 0; i < 8; ++i) {
      const int p1 = ((4 * i + h) ^ n5) * 16;
      const int p2 = ((4 * i + 2 + h) ^ n5) * 16;
      int4 b0 = *(const int4*)(bbase + p1);
      int4 b1 = *(const int4*)(bbase + p2);
      intx8 bw = {b0.x, b0.y, b0.z, b0.w, b1.x, b1.y, b1.z, b1.w};
      acc0 = __builtin_amdgcn_mfma_scale_f32_32x32x64_f8f6f4(
          aw[i], bw, acc0, 0, 0, 0, 0x7F7F7F7F, 0, 0x7F7F7F7F);
      int4 c0 = *(const int4*)(bbase + 32 * DK + p1);
      int4 c1 = *(const int4*)(bbase + 32 * DK + p2);
      intx8 cw = {c0.x, c0.y, c0.z, c0.w, c1.x, c1.y, c1.z, c1.w};
      acc1 = __builtin_amdgcn_mfma_scale_f32_32x32x64_f8f6f4(
          aw[i], cw, acc1, 0, 0, 0, 0x7F7F7F7F, 0, 0x7F7F7F7F);
    }
    __builtin_amdgcn_s_setprio(0);

    // epilogue: mask diag (aa/bb eye AND ab/ba label -- label re-added
    // exactly in finalize), exp-sum at fixed max 10.
    const int ct = csplit * 8 + t;        // 64-col tile index within view
    const bool dtile = ((ct >> 1) == rb);
    const int colbase = ct * 64;
    const bool passA = (u < 8);
#pragma unroll
    for (int r = 0; r < 16; ++r) {
      float v0 = acc0[r], v1 = acc1[r];
      if (dtile) {
        const int rowg = r0 + w * 32 + (r & 3) + 8 * (r >> 2) + 4 * h;
        if (rowg == colbase + n5)      v0 = NEG_BIG;
        if (rowg == colbase + 32 + n5) v1 = NEG_BIG;
      }
      if (passA) mx[r] = fmaxf(mx[r], fmaxf(v0, v1));
      l[r] += exp2f(fmaf(v0, SCL2, -C2)) + exp2f(fmaf(v1, SCL2, -C2));
    }

    if (u == 7) {  // pass boundary: emit full_a stats, switch to b-frags
#pragma unroll
      for (int off = 1; off < 32; off <<= 1)
#pragma unroll
        for (int r = 0; r < 16; ++r) {
          l[r] += __shfl_xor(l[r], off);
          mx[r] = fmaxf(mx[r], __shfl_xor(mx[r], off));
        }
      if (n5 == 0) {
#pragma unroll
        for (int r = 0; r < 16; ++r) {
          const int row = r0 + w * 32 + (r & 3) + 8 * (r >> 2) + 4 * h;
          pSA[split * BN + row] = l[r];
          pMA[split * BN + row] = mx[r] * SCL;  // logit-domain max
        }
      }
#pragma unroll
      for (int r = 0; r < 16; ++r) l[r] = 0.f;
      loadfrags(Bn);
    }
    __syncthreads();  // cur consumed by all waves; nxt's DMA drained
  }

  // emit full_b sums
#pragma unroll
  for (int off = 1; off < 32; off <<= 1)
#pragma unroll
    for (int r = 0; r < 16; ++r) l[r] += __shfl_xor(l[r], off);
  if (n5 == 0) {
#pragma unroll
    for (int r = 0; r < 16; ++r) {
      const int row = r0 + w * 32 + (r & 3) + 8 * (r >> 2) + 4 * h;
      pSB[split * BN + row] = l[r];
    }
  }

  // ---- fused finalize: last block to arrive merges the 16 splits --------
  __threadfence();  // release this block's partial stores (device scope)
  if (tid == 0) s_last = (atomicAdd(cnt, 1u) == (32u * 16u - 1u));
  __syncthreads();
  if (s_last) {
    __threadfence();  // acquire all other blocks' partial stores
    float lsum = 0.f, csum = 0.f;
#pragma unroll 1
    for (int it = 0; it < 16; ++it) {
      const int row = it * 256 + tid;
      float SA = 0.f, SB = 0.f, MA = NEG_BIG;
#pragma unroll
      for (int s = 0; s < NSPLIT; ++s) {
        SA += pSA[s * BN + row];
        SB += pSB[s * BN + row];
        MA = fmaxf(MA, pMA[s * BN + row]);
      }
      const float d = diag[row];
      const float eL = exp2f(fmaf(d, 1.44269504f, -C2));  // exp(d-10)
      lsum += (10.0f + logf(SA + eL) - d) + (10.0f + logf(SB + eL) - d);
      csum += (d >= MA) ? 1.f : 0.f;  // argmax(full_a)==label
    }
#pragma unroll
    for (int off = 32; off > 0; off >>= 1) {
      lsum += __shfl_xor(lsum, off);
      csum += __shfl_xor(csum, off);
    }
    float* sm = (float*)smem;  // LDS free now (all reads drained pre-barrier)
    if (lane == 0) { sm[w] = lsum; sm[4 + w] = csum; }
    __syncthreads();
    if (tid == 0) {
      const float ls = sm[0] + sm[1] + sm[2] + sm[3];
      const float cs = sm[4] + sm[5] + sm[6] + sm[7];
      out[0] = ls * (1.0f / 8192.0f);    // mean over rows, /2
      out[1] = cs * (100.0f / 4096.0f);  // accuracy %
    }
  }
}

extern "C" void kernel_launch(void* const* d_in, const int* in_sizes, int n_in,
                              void* d_out, int out_size, void* d_ws, size_t ws_size,
                              hipStream_t stream) {
  const float* A = (const float*)d_in[0];
  const float* Bv = (const float*)d_in[1];
  unsigned char* An = (unsigned char*)d_ws;                   // 4096x512 fp8
  unsigned char* Bn = An + (size_t)BN * DK;                   // 4096x512 fp8
  float* diag = (float*)(Bn + (size_t)BN * DK);               // 4096 f32
  float* pSA = diag + BN;                                     // [16][4096] f32
  float* pMA = pSA + NSPLIT * BN;                             // [16][4096] f32
  float* pSB = pMA + NSPLIT * BN;                             // [16][4096] f32
  unsigned int* cnt = (unsigned int*)(pSB + NSPLIT * BN);     // 1 u32
  float* out = (float*)d_out;

  prep_kernel<<<BN / 4, 256, 0, stream>>>(A, Bv, An, Bn, diag, out, cnt);
  tiles_kernel<<<dim3(32, 16), 256, 0, stream>>>(An, Bn, pSA, pMA, pSB,
                                                 diag, out, cnt);
}

// Round 5
// 121.908 us; speedup vs baseline: 1.3446x; 1.3446x over previous
//
#include <hip/hip_runtime.h>
#include <stdint.h>

// SimCLR loss, B=4096, D=512, TAU=0.1.  out[0]=loss, out[1]=acc(%).
//
// Round 15: SINGLE-VARIABLE ablation. Byte-exact Round-10 kernel (the 62.9us
// tiles / 124us total baseline) with ONLY the swizzle widened 3-bit -> 5-bit:
//   stage src: ^(cl&7) -> ^(cl&31);  read: ^(n5&7) -> ^n5.
// This is the exact math R13/R14 verified (absmax 0.0, SQ_LDS_BANK_CONFLICT
// 4.19M -> 0).  Everything else from R14's losing bundle is REVERTED:
// no setprio, no #pragma unroll 1, no fused finalize / threadfence / atomic
// (R14: 106us -- four confounded suspects; this round isolates the swizzle).
// R10's 4-way conflict = 4 extra cy per ds_read_b128 (~1.58x, m136) on the
// ds_read->MFMA critical path; predict tiles 62.9 -> 52-57us if binding,
// ~unchanged if the 2-phase schedule is stage-bound (m233/m252).

#define BN 4096
#define DK 512            // K elements = bytes per row in fp8
#define NSPLIT 16
#define NEG_BIG -1e30f
#define SCL 0.15625f      // 1/(8*8*TAU)
#define SCL2 0.225396744f // SCL * log2(e)
#define C2 14.4269504f    // 10 * log2(e)
#define TILE_BYTES (64 * DK)  // 32 KB per 64-col fp8 tile

typedef __attribute__((ext_vector_type(16))) float floatx16;
typedef __attribute__((ext_vector_type(8))) int intx8;

// ---------------- prep: normalize, fp8-pack (K-permuted), label, zero -----
// Permuted layout: byte position kc2*32 + h*16 + t*8 + j holds original
// k = kc2*32 + t*16 + h*8 + j.  16B chunk (kc2,h) = K=16-sub-block operand
// bytes; two consecutive chunks (2i,h),(2i+1,h) = one K=64 MX operand half.
__global__ void __launch_bounds__(256) prep_kernel(
    const float* __restrict__ A, const float* __restrict__ Bv,
    unsigned char* __restrict__ An, unsigned char* __restrict__ Bn,
    float* __restrict__ diag, float* __restrict__ out) {
  if (blockIdx.x == 0 && threadIdx.x < 2) out[threadIdx.x] = 0.0f;
  const int w = threadIdx.x >> 6, lane = threadIdx.x & 63;
  const int row = blockIdx.x * 4 + w;
  const float4* pa4 = (const float4*)(A + (size_t)row * DK);
  const float4* pb4 = (const float4*)(Bv + (size_t)row * DK);
  float4 a0 = pa4[lane * 2], a1 = pa4[lane * 2 + 1];  // k = lane*8 .. +7
  float4 b0 = pb4[lane * 2], b1 = pb4[lane * 2 + 1];
  float ssa = a0.x * a0.x + a0.y * a0.y + a0.z * a0.z + a0.w * a0.w +
              a1.x * a1.x + a1.y * a1.y + a1.z * a1.z + a1.w * a1.w;
  float ssb = b0.x * b0.x + b0.y * b0.y + b0.z * b0.z + b0.w * b0.w +
              b1.x * b1.x + b1.y * b1.y + b1.z * b1.z + b1.w * b1.w;
  float sab = a0.x * b0.x + a0.y * b0.y + a0.z * b0.z + a0.w * b0.w +
              a1.x * b1.x + a1.y * b1.y + a1.z * b1.z + a1.w * b1.w;
#pragma unroll
  for (int off = 32; off > 0; off >>= 1) {
    ssa += __shfl_xor(ssa, off);
    ssb += __shfl_xor(ssb, off);
    sab += __shfl_xor(sab, off);
  }
  float na = fmaxf(sqrtf(ssa), 1e-12f);
  float nb = fmaxf(sqrtf(ssb), 1e-12f);
  const float s = 8.0f;  // fp8 pre-scale: keeps elems mid-range in e4m3
  float sa = s / na, sb = s / nb;
  const int doff = (lane >> 2) * 32 + (lane & 1) * 16 + ((lane >> 1) & 1) * 8;
  {
    int v0 = __builtin_amdgcn_cvt_pk_fp8_f32(a0.x * sa, a0.y * sa, 0, false);
    v0 = __builtin_amdgcn_cvt_pk_fp8_f32(a0.z * sa, a0.w * sa, v0, true);
    int v1 = __builtin_amdgcn_cvt_pk_fp8_f32(a1.x * sa, a1.y * sa, 0, false);
    v1 = __builtin_amdgcn_cvt_pk_fp8_f32(a1.z * sa, a1.w * sa, v1, true);
    int2 pv; pv.x = v0; pv.y = v1;
    *(int2*)(An + (size_t)row * DK + doff) = pv;
  }
  {
    int v0 = __builtin_amdgcn_cvt_pk_fp8_f32(b0.x * sb, b0.y * sb, 0, false);
    v0 = __builtin_amdgcn_cvt_pk_fp8_f32(b0.z * sb, b0.w * sb, v0, true);
    int v1 = __builtin_amdgcn_cvt_pk_fp8_f32(b1.x * sb, b1.y * sb, 0, false);
    v1 = __builtin_amdgcn_cvt_pk_fp8_f32(b1.z * sb, b1.w * sb, v1, true);
    int2 pv; pv.x = v0; pv.y = v1;
    *(int2*)(Bn + (size_t)row * DK + doff) = pv;
  }
  if (lane == 0) diag[row] = (sab / (na * nb)) * 10.0f;  // exact fp32 /TAU
}

// ---------------- tiles: MX fp8 MFMA, 128-row blocks, 2 passes, dbuf ------
// grid = (32 row-blocks, 16 col-splits) = 512 blocks = 2/CU. 4 waves/block,
// wave owns 32 rows. Pass 0 (u<8): a-frags -> full_a sum+max. Pass 1:
// b-frags -> full_b sums. Tiles restaged per pass (4MB dataset, L2-hot).
__global__ void __launch_bounds__(256, 2) tiles_kernel(
    const unsigned char* __restrict__ An, const unsigned char* __restrict__ Bn,
    float* __restrict__ pSA, float* __restrict__ pMA, float* __restrict__ pSB) {
  __shared__ __align__(16) unsigned char smem[2 * TILE_BYTES];  // 64 KB

  const int rb = blockIdx.x;     // 0..31 (128-row panel)
  const int split = blockIdx.y;  // 0..15 (8 j-tiles each)
  const int tid = threadIdx.x;
  const int lane = tid & 63, w = tid >> 6;
  const int n5 = lane & 31, h = lane >> 5;
  const int r0 = rb * 128;
  const int myrow = r0 + w * 32 + n5;

  // one view's left K=64 MX operands: aw[i] = chunks (2i,h)||(2i+1,h)
  intx8 aw[8];
  auto loadfrags = [&](const unsigned char* base) {
    const unsigned char* p = base + (size_t)myrow * DK + h * 16;
#pragma unroll
    for (int i = 0; i < 8; ++i) {
      int4 c0 = *(const int4*)(p + i * 64);        // chunk kc2=2i
      int4 c1 = *(const int4*)(p + i * 64 + 32);   // chunk kc2=2i+1
      intx8 v = {c0.x, c0.y, c0.z, c0.w, c1.x, c1.y, c1.z, c1.w};
      aw[i] = v;
    }
  };

  // fixed-max state: l[r] = sum exp(logit-10); mx[r] = max acc (pass A only)
  float l[16], mx[16];
#pragma unroll
  for (int r = 0; r < 16; ++r) { l[r] = 0.f; mx[r] = NEG_BIG; }

  // stage a 64-col fp8 tile; one inst = 2 cols (h=0 even, h=1 odd).
  // 5-bit XOR swizzle: physical 16B chunk p of col c holds logical p^(c&31).
  auto stage = [&](unsigned char* buf, int jt) {
    const unsigned char* csrc = (jt < 64) ? An : Bn;
    const int cb = (jt & 63) * 64;
#pragma unroll
    for (int ii = 0; ii < 8; ++ii) {  // wave w: colpairs w*8 .. w*8+7
      const int cp = w * 8 + ii;
      const int cl = cp * 2 + h;
      const unsigned char* src =
          csrc + (size_t)(cb + cl) * DK + ((n5 ^ (cl & 31)) * 16);
      __builtin_amdgcn_global_load_lds(
          (const __attribute__((address_space(1))) void*)src,
          (__attribute__((address_space(3))) void*)(buf + cp * 1024),
          16, 0, 0);
    }
  };

  stage(smem, split * 8);
  loadfrags(An);
  __syncthreads();

  for (int u = 0; u < 16; ++u) {
    const int t = u & 7;
    const int jt = split * 8 + t;
    unsigned char* cur = smem + (u & 1) * TILE_BYTES;
    unsigned char* nxt = smem + ((u + 1) & 1) * TILE_BYTES;
    if (u < 15) stage(nxt, split * 8 + ((t + 1) & 7));  // prefetch

    floatx16 acc[2];
#pragma unroll
    for (int cs = 0; cs < 2; ++cs)
#pragma unroll
      for (int r = 0; r < 16; ++r) acc[cs][r] = 0.f;

    // B K=64 operand: logical chunks (4i+h) and (4i+2+h) of col cs*32+n5
    const unsigned char* bbase = cur + (size_t)n5 * DK;
#pragma unroll
    for (int i = 0; i < 8; ++i) {
      const int p1 = ((4 * i + h) ^ n5) * 16;
      const int p2 = ((4 * i + 2 + h) ^ n5) * 16;
#pragma unroll
      for (int cs = 0; cs < 2; ++cs) {
        int4 b0 = *(const int4*)(bbase + cs * 32 * DK + p1);
        int4 b1 = *(const int4*)(bbase + cs * 32 * DK + p2);
        intx8 bw = {b0.x, b0.y, b0.z, b0.w, b1.x, b1.y, b1.z, b1.w};
        acc[cs] = __builtin_amdgcn_mfma_scale_f32_32x32x64_f8f6f4(
            aw[i], bw, acc[cs], 0, 0, 0, 0x7F7F7F7F, 0, 0x7F7F7F7F);
      }
    }

    // epilogue: mask (i,i) of this half (aa/bb masked diag AND ab label —
    // label re-added exactly in finalize), exp-sum at fixed max 10.
    const bool dtile = (((jt & 63) >> 1) == rb);
    const int colbase = (jt & 63) * 64;
    const bool passA = (u < 8);
#pragma unroll
    for (int r = 0; r < 16; ++r) {
      float v0 = acc[0][r], v1 = acc[1][r];
      if (dtile) {
        const int rowg = r0 + w * 32 + (r & 3) + 8 * (r >> 2) + 4 * h;
        if (rowg == colbase + n5)      v0 = NEG_BIG;
        if (rowg == colbase + 32 + n5) v1 = NEG_BIG;
      }
      if (passA) mx[r] = fmaxf(mx[r], fmaxf(v0, v1));
      l[r] += exp2f(fmaf(v0, SCL2, -C2)) + exp2f(fmaf(v1, SCL2, -C2));
    }

    if (u == 7) {  // pass boundary: emit full_a stats, switch to b-frags
#pragma unroll
      for (int off = 1; off < 32; off <<= 1)
#pragma unroll
        for (int r = 0; r < 16; ++r) {
          l[r] += __shfl_xor(l[r], off);
          mx[r] = fmaxf(mx[r], __shfl_xor(mx[r], off));
        }
      if (n5 == 0) {
#pragma unroll
        for (int r = 0; r < 16; ++r) {
          const int row = r0 + w * 32 + (r & 3) + 8 * (r >> 2) + 4 * h;
          pSA[split * BN + row] = l[r];
          pMA[split * BN + row] = mx[r] * SCL;  // logit-domain max
        }
      }
#pragma unroll
      for (int r = 0; r < 16; ++r) l[r] = 0.f;
      loadfrags(Bn);
    }
    __syncthreads();  // cur consumed; nxt's DMA drained
  }

  // emit full_b sums
#pragma unroll
  for (int off = 1; off < 32; off <<= 1)
#pragma unroll
    for (int r = 0; r < 16; ++r) l[r] += __shfl_xor(l[r], off);
  if (n5 == 0) {
#pragma unroll
    for (int r = 0; r < 16; ++r) {
      const int row = r0 + w * 32 + (r & 3) + 8 * (r >> 2) + 4 * h;
      pSB[split * BN + row] = l[r];
    }
  }
}

// ---------------- finalize: merge 16 splits, add label, reduce ------------
__global__ void __launch_bounds__(256) finalize_kernel(
    const float* __restrict__ pSA, const float* __restrict__ pMA,
    const float* __restrict__ pSB, const float* __restrict__ diag,
    float* __restrict__ out) {
  const int row = blockIdx.x * 256 + threadIdx.x;
  float SA = 0.f, SB = 0.f, MA = NEG_BIG;
#pragma unroll
  for (int s = 0; s < NSPLIT; ++s) {
    SA += pSA[s * BN + row];
    SB += pSB[s * BN + row];
    MA = fmaxf(MA, pMA[s * BN + row]);
  }
  const float d = diag[row];
  const float eL = exp2f(fmaf(d, 1.44269504f, -C2));  // exp(d-10)
  float lseA = 10.0f + logf(SA + eL);
  float lseB = 10.0f + logf(SB + eL);
  float lossi = (lseA - d) + (lseB - d);
  float corr = (d >= MA) ? 1.f : 0.f;  // argmax(full_a)==label
#pragma unroll
  for (int off = 32; off > 0; off >>= 1) {
    lossi += __shfl_xor(lossi, off);
    corr += __shfl_xor(corr, off);
  }
  __shared__ float sred[2][4];
  if ((threadIdx.x & 63) == 0) {
    int w = threadIdx.x >> 6;
    sred[0][w] = lossi; sred[1][w] = corr;
  }
  __syncthreads();
  if (threadIdx.x == 0) {
    float ls = sred[0][0] + sred[0][1] + sred[0][2] + sred[0][3];
    float cs = sred[1][0] + sred[1][1] + sred[1][2] + sred[1][3];
    atomicAdd(&out[0], ls * (1.0f / 8192.0f));    // mean over rows, /2
    atomicAdd(&out[1], cs * (100.0f / 4096.0f));  // accuracy %
  }
}

extern "C" void kernel_launch(void* const* d_in, const int* in_sizes, int n_in,
                              void* d_out, int out_size, void* d_ws, size_t ws_size,
                              hipStream_t stream) {
  const float* A = (const float*)d_in[0];
  const float* Bv = (const float*)d_in[1];
  unsigned char* An = (unsigned char*)d_ws;                   // 4096x512 fp8
  unsigned char* Bn = An + (size_t)BN * DK;                   // 4096x512 fp8
  float* diag = (float*)(Bn + (size_t)BN * DK);               // 4096 f32
  float* pSA = diag + BN;                                     // [16][4096] f32
  float* pMA = pSA + NSPLIT * BN;                             // [16][4096] f32
  float* pSB = pMA + NSPLIT * BN;                             // [16][4096] f32
  float* out = (float*)d_out;

  prep_kernel<<<BN / 4, 256, 0, stream>>>(A, Bv, An, Bn, diag, out);
  tiles_kernel<<<dim3(32, 16), 256, 0, stream>>>(An, Bn, pSA, pMA, pSB);
  finalize_kernel<<<BN / 256, 256, 0, stream>>>(pSA, pMA, pSB, diag, out);
}